// Round 1
// baseline (888.195 us; speedup 1.0000x reference)
//
#include <hip/hip_runtime.h>
#include <math.h>

// Problem constants
#define BD   64      // batch
#define TD   2048    // seq
#define DD   1024    // D
#define HD   256     // H
#define KD   64      // K prototypes
#define CTXW 16

// ws layout (float offsets)
#define OFF_XPART  0u                         // 64*16*1024 = 1048576
#define OFF_H1P    1048576u                   // 16*256
#define OFF_H2P    1052672u                   // 16*1024
#define OFF_CTXENC 1069056u                   // 1024
#define OFF_ACTION 1070080u                   // 64*1024
#define OFF_PROTOP 1135616u                   // 64*512
#define OFF_S1P    1168384u                   // 16*256
#define OFF_CCP    1172480u                   // 16*512
#define OFF_AAP    1180672u                   // 8*64*512
#define OFF_SVC    1442816u                   // 8*256
#define OFF_SVA    1444864u                   // 8*64*256  -> end 1575936 floats (~6.0 MB)

__device__ __forceinline__ float geluf(float v) {
    return 0.5f * v * (1.0f + erff(v * 0.70710678118654752f));
}
__device__ __forceinline__ float sigm(float v) {
    return 1.0f / (1.0f + expf(-v));
}

// ---------------- K1: x partial sums + h1 split-K partials + proto @ wp ----------------
__global__ __launch_bounds__(256) void k1(const float* __restrict__ x,
                                          const float* __restrict__ cb,
                                          const float* __restrict__ proto,
                                          const float* __restrict__ ce_w1,
                                          const float* __restrict__ nm_w1,
                                          float* __restrict__ ws) {
    const int blk = blockIdx.x;
    const int t = threadIdx.x;
    if (blk < 1024) {
        // x partial sums: block = (b, tchunk of 128)
        const int b = blk >> 4, tc = blk & 15;
        const float4* xp = (const float4*)(x + (size_t)(b * TD + tc * 128) * DD);
        float4 acc = make_float4(0.f, 0.f, 0.f, 0.f);
        const float4* p = xp + t;
        #pragma unroll 4
        for (int i = 0; i < 128; ++i) {
            float4 v = p[(size_t)i * 256];
            acc.x += v.x; acc.y += v.y; acc.z += v.z; acc.w += v.w;
        }
        ((float4*)(ws + OFF_XPART + (size_t)blk * DD))[t] = acc;
    } else if (blk < 1040) {
        // h1 partial: d-chunk of 64; recompute ctx slice locally
        const int k = blk - 1024;
        __shared__ float ctxv[64];
        if (t < 64) {
            int d = k * 64 + t;
            float s = 0.f;
            #pragma unroll
            for (int w = 0; w < CTXW; ++w) s += cb[w * DD + d];
            ctxv[t] = s * (1.0f / 16.0f);
        }
        __syncthreads();
        float acc = 0.f;
        #pragma unroll 8
        for (int d = 0; d < 64; ++d)
            acc += ctxv[d] * ce_w1[(size_t)(k * 64 + d) * HD + t];
        ws[OFF_H1P + k * HD + t] = acc;
    } else {
        // protopre[p][j] = proto[p] @ wp[:,j]  (wp = nm_w1 rows 2048..3071)
        const int idx = blk - 1040;
        const int pg = idx >> 1, jh = idx & 1;
        __shared__ float pr[8][1024];
        for (int i = t; i < 8 * 1024; i += 256) pr[i >> 10][i & 1023] = proto[(size_t)(pg * 8) * DD + i];
        __syncthreads();
        const int j = jh * 256 + t;
        float acc[8];
        #pragma unroll
        for (int p = 0; p < 8; ++p) acc[p] = 0.f;
        for (int d = 0; d < DD; ++d) {
            float w = nm_w1[(size_t)(2048 + d) * 512 + j];
            #pragma unroll
            for (int p = 0; p < 8; ++p) acc[p] += pr[p][d] * w;
        }
        #pragma unroll
        for (int p = 0; p < 8; ++p) ws[OFF_PROTOP + (size_t)(pg * 8 + p) * 512 + j] = acc[p];
    }
}

// ---------------- K2: h2 partials + action reduce ----------------
__global__ __launch_bounds__(256) void k2(const float* __restrict__ ce_b1,
                                          const float* __restrict__ ce_w2,
                                          float* __restrict__ ws) {
    const int blk = blockIdx.x;
    const int t = threadIdx.x;
    if (blk < 16) {
        // h2 partial: h-range [blk*16, blk*16+16)
        __shared__ float g1[16];
        if (t < 16) {
            int h = blk * 16 + t;
            float s = ce_b1[h];
            #pragma unroll
            for (int p = 0; p < 16; ++p) s += ws[OFF_H1P + p * HD + h];
            g1[t] = geluf(s);
        }
        __syncthreads();
        float4 acc = make_float4(0.f, 0.f, 0.f, 0.f);
        #pragma unroll
        for (int i = 0; i < 16; ++i) {
            float g = g1[i];
            float4 w = ((const float4*)(ce_w2 + (size_t)(blk * 16 + i) * DD))[t];
            acc.x += g * w.x; acc.y += g * w.y; acc.z += g * w.z; acc.w += g * w.w;
        }
        ((float4*)(ws + OFF_H2P + (size_t)blk * DD))[t] = acc;
    } else {
        // action[b] = sum of 16 partials / 2048
        const int b = blk - 16;
        float4 acc = make_float4(0.f, 0.f, 0.f, 0.f);
        #pragma unroll
        for (int k = 0; k < 16; ++k) {
            float4 v = ((const float4*)(ws + OFF_XPART + (size_t)(b * 16 + k) * DD))[t];
            acc.x += v.x; acc.y += v.y; acc.z += v.z; acc.w += v.w;
        }
        const float inv = 1.0f / 2048.0f;
        acc.x *= inv; acc.y *= inv; acc.z *= inv; acc.w *= inv;
        ((float4*)(ws + OFF_ACTION + (size_t)b * DD))[t] = acc;
    }
}

// ---------------- K3: reduce h2 + RMS norm -> ctx_enc ----------------
__global__ __launch_bounds__(256) void k3(const float* __restrict__ ce_b2,
                                          const float* __restrict__ rms_w,
                                          float* __restrict__ ws) {
    const int t = threadIdx.x;
    float4 acc = ((const float4*)ce_b2)[t];
    #pragma unroll
    for (int k = 0; k < 16; ++k) {
        float4 v = ((const float4*)(ws + OFF_H2P + (size_t)k * DD))[t];
        acc.x += v.x; acc.y += v.y; acc.z += v.z; acc.w += v.w;
    }
    float ss = acc.x * acc.x + acc.y * acc.y + acc.z * acc.z + acc.w * acc.w;
    // block reduce over 4 waves
    __shared__ float red[4];
    __shared__ float totsh;
    const int wave = t >> 6, lane = t & 63;
    #pragma unroll
    for (int o = 32; o >= 1; o >>= 1) ss += __shfl_xor(ss, o);
    if (lane == 0) red[wave] = ss;
    __syncthreads();
    if (t == 0) totsh = red[0] + red[1] + red[2] + red[3];
    __syncthreads();
    float r = rsqrtf(totsh * (1.0f / 1024.0f) + 1e-6f);
    float4 w = ((const float4*)rms_w)[t];
    acc.x *= r * w.x; acc.y *= r * w.y; acc.z *= r * w.z; acc.w *= r * w.w;
    ((float4*)(ws + OFF_CTXENC))[t] = acc;
}

// ---------------- K4: aa partials, sv partials, s1 partials, cc partials ----------------
__global__ __launch_bounds__(256) void k4(const float* __restrict__ nm_w1,
                                          const float* __restrict__ ns_w1,
                                          const float* __restrict__ sv_w1,
                                          float* __restrict__ ws) {
    const int blk = blockIdx.x;
    const int t = threadIdx.x;
    if (blk < 64) {
        // aa partial: action @ wa (wa = nm_w1 rows 1024..2047). dc in [0,8) over d, bg in [0,8) over b
        const int dc = blk >> 3, bg = blk & 7;
        __shared__ float al[8][128];
        for (int i = t; i < 8 * 128; i += 256) {
            int p = i >> 7, d = i & 127;
            al[p][d] = ws[OFF_ACTION + (size_t)(bg * 8 + p) * DD + dc * 128 + d];
        }
        __syncthreads();
        float acc0[8], acc1[8];
        #pragma unroll
        for (int p = 0; p < 8; ++p) { acc0[p] = 0.f; acc1[p] = 0.f; }
        for (int d = 0; d < 128; ++d) {
            const float* wrow = nm_w1 + (size_t)(1024 + dc * 128 + d) * 512;
            float w0 = wrow[t], w1 = wrow[t + 256];
            #pragma unroll
            for (int p = 0; p < 8; ++p) {
                float a = al[p][d];
                acc0[p] += a * w0; acc1[p] += a * w1;
            }
        }
        #pragma unroll
        for (int p = 0; p < 8; ++p) {
            size_t base = OFF_AAP + (size_t)(dc * 64 + bg * 8 + p) * 512;
            ws[base + t] = acc0[p];
            ws[base + t + 256] = acc1[p];
        }
    } else if (blk < 72) {
        // sv ctx-half partial (b-independent): dc in [0,8) over ctx_enc d
        const int dc = blk - 64;
        float acc = 0.f;
        #pragma unroll 4
        for (int d = 0; d < 128; ++d)
            acc += ws[OFF_CTXENC + dc * 128 + d] * sv_w1[(size_t)(dc * 128 + d) * HD + t];
        ws[OFF_SVC + dc * HD + t] = acc;
    } else if (blk < 136) {
        // sv action-half partial
        const int ii = blk - 72;
        const int dc = ii >> 3, bg = ii & 7;
        __shared__ float al[8][128];
        for (int i = t; i < 8 * 128; i += 256) {
            int p = i >> 7, d = i & 127;
            al[p][d] = ws[OFF_ACTION + (size_t)(bg * 8 + p) * DD + dc * 128 + d];
        }
        __syncthreads();
        float acc[8];
        #pragma unroll
        for (int p = 0; p < 8; ++p) acc[p] = 0.f;
        for (int d = 0; d < 128; ++d) {
            float w = sv_w1[(size_t)(1024 + dc * 128 + d) * HD + t];
            #pragma unroll
            for (int p = 0; p < 8; ++p) acc[p] += al[p][d] * w;
        }
        #pragma unroll
        for (int p = 0; p < 8; ++p)
            ws[OFF_SVA + (size_t)(dc * 64 + bg * 8 + p) * HD + t] = acc[p];
    } else if (blk < 152) {
        // s1 partial: ctx_enc @ ns_w1, dc chunks of 64
        const int k = blk - 136;
        float acc = 0.f;
        #pragma unroll 4
        for (int d = 0; d < 64; ++d)
            acc += ws[OFF_CTXENC + k * 64 + d] * ns_w1[(size_t)(k * 64 + d) * HD + t];
        ws[OFF_S1P + k * HD + t] = acc;
    } else {
        // cc partial: ctx_enc @ wc (nm_w1 rows 0..1023), dc chunks of 64
        const int k = blk - 152;
        float a0 = 0.f, a1 = 0.f;
        #pragma unroll 4
        for (int d = 0; d < 64; ++d) {
            float c = ws[OFF_CTXENC + k * 64 + d];
            const float* r = nm_w1 + (size_t)(k * 64 + d) * 512;
            a0 += c * r[t]; a1 += c * r[t + 256];
        }
        ws[OFF_CCP + k * 512 + t] = a0;
        ws[OFF_CCP + k * 512 + t + 256] = a1;
    }
}

// ---------------- K5: per-b final: softmax weights, conformance, severity, outputs ----------------
__global__ __launch_bounds__(256) void k5(const float* __restrict__ ns_b1,
                                          const float* __restrict__ ns_w2,
                                          const float* __restrict__ ns_b2,
                                          const float* __restrict__ nm_b1,
                                          const float* __restrict__ nm_w2,
                                          const float* __restrict__ nm_b2,
                                          const float* __restrict__ sv_b1,
                                          const float* __restrict__ sv_w2,
                                          const float* __restrict__ sv_b2,
                                          const float* __restrict__ ws,
                                          float* __restrict__ out) {
    const int b = blockIdx.x;
    const int t = threadIdx.x;
    const int wave = t >> 6, lane = t & 63;
    __shared__ float g1[256];
    __shared__ float nw[64];
    __shared__ float base[512];
    __shared__ float w2s[512];
    __shared__ float conf[64];
    __shared__ float red[4];

    // g1 = gelu(ctx_enc @ ns_w1 + ns_b1)
    {
        float s = ns_b1[t];
        #pragma unroll
        for (int k = 0; k < 16; ++k) s += ws[OFF_S1P + k * HD + t];
        g1[t] = geluf(s);
    }
    __syncthreads();
    // norm weights: softmax over 64 logits (wave 0 only)
    if (t < 64) {
        float s = ns_b2[t];
        for (int h = 0; h < HD; ++h) s += g1[h] * ns_w2[(size_t)h * 64 + t];
        float m = s;
        #pragma unroll
        for (int o = 32; o >= 1; o >>= 1) m = fmaxf(m, __shfl_xor(m, o));
        float e = expf(s - m);
        float tot = e;
        #pragma unroll
        for (int o = 32; o >= 1; o >>= 1) tot += __shfl_xor(tot, o);
        nw[t] = e / tot;
    }
    // base[j] = cc[j] + aa[b][j] + nm_b1[j]; cache nm_w2 in LDS
    #pragma unroll
    for (int jj = 0; jj < 2; ++jj) {
        int j = t + jj * 256;
        float v = nm_b1[j];
        #pragma unroll
        for (int k = 0; k < 16; ++k) v += ws[OFF_CCP + k * 512 + j];
        #pragma unroll
        for (int k = 0; k < 8; ++k) v += ws[OFF_AAP + (size_t)(k * 64 + b) * 512 + j];
        base[j] = v;
        w2s[j] = nm_w2[j];
    }
    __syncthreads();
    // conformance[p] = sigmoid(sum_j gelu(base[j] + protopre[p][j]) * nm_w2[j] + nm_b2)
    const float b2 = nm_b2[0];
    for (int pi = 0; pi < 16; ++pi) {
        int p = wave * 16 + pi;
        const float* pp = ws + OFF_PROTOP + (size_t)p * 512;
        float s = 0.f;
        #pragma unroll
        for (int i = 0; i < 8; ++i) {
            int j = lane + 64 * i;
            s += geluf(base[j] + pp[j]) * w2s[j];
        }
        #pragma unroll
        for (int o = 32; o >= 1; o >>= 1) s += __shfl_xor(s, o);
        if (lane == 0) conf[p] = sigm(s + b2);
    }
    // severity: sv1[h] = gelu(sum partials + sv_b1); dot with sv_w2
    float sv = sv_b1[t];
    #pragma unroll
    for (int k = 0; k < 8; ++k) sv += ws[OFF_SVC + k * HD + t];
    #pragma unroll
    for (int k = 0; k < 8; ++k) sv += ws[OFF_SVA + (size_t)(k * 64 + b) * HD + t];
    float part = geluf(sv) * sv_w2[t];
    #pragma unroll
    for (int o = 32; o >= 1; o >>= 1) part += __shfl_xor(part, o);
    if (lane == 0) red[wave] = part;
    __syncthreads();
    if (t < 64) {
        float wcp = conf[t] * nw[t];
        #pragma unroll
        for (int o = 32; o >= 1; o >>= 1) wcp += __shfl_xor(wcp, o);
        if (t == 0) {
            float sev = sigm(red[0] + red[1] + red[2] + red[3] + sv_b2[0]);
            float wcf = wcp;
            float viol = 1.0f - wcf;
            out[b] = viol * sev * 0.1f;
            out[64 + b] = wcf;
            out[128 + b] = viol;
            out[192 + b] = sev;
        }
    }
}

extern "C" void kernel_launch(void* const* d_in, const int* in_sizes, int n_in,
                              void* d_out, int out_size, void* d_ws, size_t ws_size,
                              hipStream_t stream) {
    const float* x      = (const float*)d_in[0];
    const float* cb     = (const float*)d_in[1];
    const float* proto  = (const float*)d_in[2];
    const float* ce_w1  = (const float*)d_in[3];
    const float* ce_b1  = (const float*)d_in[4];
    const float* ce_w2  = (const float*)d_in[5];
    const float* ce_b2  = (const float*)d_in[6];
    const float* rms_w  = (const float*)d_in[7];
    const float* nm_w1  = (const float*)d_in[8];
    const float* nm_b1  = (const float*)d_in[9];
    const float* nm_w2  = (const float*)d_in[10];
    const float* nm_b2  = (const float*)d_in[11];
    const float* ns_w1  = (const float*)d_in[12];
    const float* ns_b1  = (const float*)d_in[13];
    const float* ns_w2  = (const float*)d_in[14];
    const float* ns_b2  = (const float*)d_in[15];
    const float* sv_w1  = (const float*)d_in[16];
    const float* sv_b1  = (const float*)d_in[17];
    const float* sv_w2  = (const float*)d_in[18];
    const float* sv_b2  = (const float*)d_in[19];
    float* ws  = (float*)d_ws;
    float* out = (float*)d_out;

    hipLaunchKernelGGL(k1, dim3(1056), dim3(256), 0, stream, x, cb, proto, ce_w1, nm_w1, ws);
    hipLaunchKernelGGL(k2, dim3(80), dim3(256), 0, stream, ce_b1, ce_w2, ws);
    hipLaunchKernelGGL(k3, dim3(1), dim3(256), 0, stream, ce_b2, rms_w, ws);
    hipLaunchKernelGGL(k4, dim3(168), dim3(256), 0, stream, nm_w1, ns_w1, sv_w1, ws);
    hipLaunchKernelGGL(k5, dim3(64), dim3(256), 0, stream,
                       ns_b1, ns_w2, ns_b2, nm_b1, nm_w2, nm_b2, sv_b1, sv_w2, sv_b2, ws, out);
}

// Round 2
// 845.864 us; speedup vs baseline: 1.0500x; 1.0500x over previous
//
#include <hip/hip_runtime.h>
#include <math.h>

// Problem constants
#define BD   64      // batch
#define TD   2048    // seq
#define DD   1024    // D
#define HD   256     // H
#define KD   64      // K prototypes
#define CTXW 16

// ws layout (float offsets)
#define OFF_XPART  0u                         // 64*16*1024 = 1048576
#define OFF_H1P    1048576u                   // 16*256
#define OFF_H2P    1052672u                   // 16*1024
#define OFF_PROTOP 1135616u                   // 64*512
#define OFF_S1P    1168384u                   // 16*256
#define OFF_CCP    1172480u                   // 16*512
#define OFF_AAP    1180672u                   // 8*64*512
#define OFF_SVC    1442816u                   // 8*256
#define OFF_SVA    1444864u                   // 8*64*256  -> end 1575936 floats (~6.0 MB)

typedef float f4 __attribute__((ext_vector_type(4)));

__device__ __forceinline__ float geluf(float v) {
    return 0.5f * v * (1.0f + erff(v * 0.70710678118654752f));
}
__device__ __forceinline__ float sigm(float v) {
    return 1.0f / (1.0f + expf(-v));
}

// ---------------- K1: h1 split-K partials + proto @ wp + x partial sums ----------------
// Small blocks FIRST so they dispatch early and hide under the x stream.
__global__ __launch_bounds__(256) void k1(const float* __restrict__ x,
                                          const float* __restrict__ cb,
                                          const float* __restrict__ proto,
                                          const float* __restrict__ ce_w1,
                                          const float* __restrict__ nm_w1,
                                          float* __restrict__ ws) {
    const int blk = blockIdx.x;
    const int t = threadIdx.x;
    if (blk < 16) {
        // h1 partial: d-chunk of 64; recompute ctx slice locally
        const int k = blk;
        __shared__ float ctxv[64];
        if (t < 64) {
            int d = k * 64 + t;
            float s = 0.f;
            #pragma unroll
            for (int w = 0; w < CTXW; ++w) s += cb[w * DD + d];
            ctxv[t] = s * (1.0f / 16.0f);
        }
        __syncthreads();
        float acc = 0.f;
        #pragma unroll 8
        for (int d = 0; d < 64; ++d)
            acc += ctxv[d] * ce_w1[(size_t)(k * 64 + d) * HD + t];
        ws[OFF_H1P + k * HD + t] = acc;
    } else if (blk < 32) {
        // protopre[p][j] = proto[p] @ wp[:,j]  (wp = nm_w1 rows 2048..3071)
        const int idx = blk - 16;
        const int pg = idx >> 1, jh = idx & 1;
        __shared__ float pr[8][1024];
        for (int i = t; i < 8 * 1024; i += 256) pr[i >> 10][i & 1023] = proto[(size_t)(pg * 8) * DD + i];
        __syncthreads();
        const int j = jh * 256 + t;
        float acc[8];
        #pragma unroll
        for (int p = 0; p < 8; ++p) acc[p] = 0.f;
        #pragma unroll 4
        for (int d = 0; d < DD; ++d) {
            float w = nm_w1[(size_t)(2048 + d) * 512 + j];
            #pragma unroll
            for (int p = 0; p < 8; ++p) acc[p] += pr[p][d] * w;
        }
        #pragma unroll
        for (int p = 0; p < 8; ++p) ws[OFF_PROTOP + (size_t)(pg * 8 + p) * 512 + j] = acc[p];
    } else {
        // x partial sums: block = (b, tchunk of 128 rows)
        const int xb = blk - 32;
        const int b = xb >> 4, tc = xb & 15;
        const f4* p = (const f4*)(x + (size_t)(b * TD + tc * 128) * DD) + t;
        f4 acc = {0.f, 0.f, 0.f, 0.f};
        #pragma unroll 8
        for (int i = 0; i < 128; ++i) {
            f4 v = __builtin_nontemporal_load(p + (size_t)i * 256);
            acc += v;
        }
        ((f4*)(ws + OFF_XPART + (size_t)xb * DD))[t] = acc;
    }
}

// ---------------- K2: h2 partials (16 blocks) ----------------
__global__ __launch_bounds__(256) void k2(const float* __restrict__ ce_b1,
                                          const float* __restrict__ ce_w2,
                                          float* __restrict__ ws) {
    const int blk = blockIdx.x;
    const int t = threadIdx.x;
    // h2 partial: h-range [blk*16, blk*16+16)
    __shared__ float g1[16];
    if (t < 16) {
        int h = blk * 16 + t;
        float s = ce_b1[h];
        #pragma unroll
        for (int p = 0; p < 16; ++p) s += ws[OFF_H1P + p * HD + h];
        g1[t] = geluf(s);
    }
    __syncthreads();
    float4 acc = make_float4(0.f, 0.f, 0.f, 0.f);
    #pragma unroll
    for (int i = 0; i < 16; ++i) {
        float g = g1[i];
        float4 w = ((const float4*)(ce_w2 + (size_t)(blk * 16 + i) * DD))[t];
        acc.x += g * w.x; acc.y += g * w.y; acc.z += g * w.z; acc.w += g * w.w;
    }
    ((float4*)(ws + OFF_H2P + (size_t)blk * DD))[t] = acc;
}

// ---------------- K4: aa partials, sv partials, s1 partials, cc partials ----------------
// ctx_enc and action are recomputed locally from partials (removes former k3 and
// k2's action branch from the serial chain).
__global__ __launch_bounds__(256) void k4(const float* __restrict__ nm_w1,
                                          const float* __restrict__ ns_w1,
                                          const float* __restrict__ sv_w1,
                                          const float* __restrict__ ce_b2,
                                          const float* __restrict__ rms_w,
                                          float* __restrict__ ws) {
    const int blk = blockIdx.x;
    const int t = threadIdx.x;
    __shared__ float al[8][128];
    __shared__ float ce[1024];
    __shared__ float red[4];
    __shared__ float totsh;

    if (blk < 128) {
        // action-slice build: bg over b-groups of 8, dc over d-chunks of 128
        const int ii = (blk < 64) ? blk : (blk - 64);
        const int dc = ii >> 3, bg = ii & 7;
        for (int i = t; i < 1024; i += 256) {
            int p = i >> 7, d = i & 127;
            int row = (bg * 8 + p) * 16;
            float s = 0.f;
            #pragma unroll
            for (int k = 0; k < 16; ++k)
                s += ws[OFF_XPART + (size_t)(row + k) * DD + dc * 128 + d];
            al[p][d] = s * (1.0f / 2048.0f);
        }
        __syncthreads();
        if (blk < 64) {
            // aa partial: action @ wa (wa = nm_w1 rows 1024..2047)
            float acc0[8], acc1[8];
            #pragma unroll
            for (int p = 0; p < 8; ++p) { acc0[p] = 0.f; acc1[p] = 0.f; }
            for (int d = 0; d < 128; ++d) {
                const float* wrow = nm_w1 + (size_t)(1024 + dc * 128 + d) * 512;
                float w0 = wrow[t], w1 = wrow[t + 256];
                #pragma unroll
                for (int p = 0; p < 8; ++p) {
                    float a = al[p][d];
                    acc0[p] += a * w0; acc1[p] += a * w1;
                }
            }
            #pragma unroll
            for (int p = 0; p < 8; ++p) {
                size_t base = OFF_AAP + (size_t)(dc * 64 + bg * 8 + p) * 512;
                ws[base + t] = acc0[p];
                ws[base + t + 256] = acc1[p];
            }
        } else {
            // sv action-half partial
            float acc[8];
            #pragma unroll
            for (int p = 0; p < 8; ++p) acc[p] = 0.f;
            for (int d = 0; d < 128; ++d) {
                float w = sv_w1[(size_t)(1024 + dc * 128 + d) * HD + t];
                #pragma unroll
                for (int p = 0; p < 8; ++p) acc[p] += al[p][d] * w;
            }
            #pragma unroll
            for (int p = 0; p < 8; ++p)
                ws[OFF_SVA + (size_t)(dc * 64 + bg * 8 + p) * HD + t] = acc[p];
        }
    } else {
        // Recompute ctx_enc from h2 partials (64 KB L2 read + block reduce)
        float4 acc = ((const float4*)ce_b2)[t];
        #pragma unroll
        for (int k = 0; k < 16; ++k) {
            float4 v = ((const float4*)(ws + OFF_H2P + (size_t)k * DD))[t];
            acc.x += v.x; acc.y += v.y; acc.z += v.z; acc.w += v.w;
        }
        float ss = acc.x * acc.x + acc.y * acc.y + acc.z * acc.z + acc.w * acc.w;
        const int wave = t >> 6, lane = t & 63;
        #pragma unroll
        for (int o = 32; o >= 1; o >>= 1) ss += __shfl_xor(ss, o);
        if (lane == 0) red[wave] = ss;
        __syncthreads();
        if (t == 0) totsh = red[0] + red[1] + red[2] + red[3];
        __syncthreads();
        float r = rsqrtf(totsh * (1.0f / 1024.0f) + 1e-6f);
        float4 w = ((const float4*)rms_w)[t];
        ce[4 * t + 0] = acc.x * r * w.x;
        ce[4 * t + 1] = acc.y * r * w.y;
        ce[4 * t + 2] = acc.z * r * w.z;
        ce[4 * t + 3] = acc.w * r * w.w;
        __syncthreads();

        if (blk < 136) {
            // sv ctx-half partial: dc in [0,8)
            const int dc = blk - 128;
            float a = 0.f;
            #pragma unroll 4
            for (int d = 0; d < 128; ++d)
                a += ce[dc * 128 + d] * sv_w1[(size_t)(dc * 128 + d) * HD + t];
            ws[OFF_SVC + dc * HD + t] = a;
        } else if (blk < 152) {
            // s1 partial: ctx_enc @ ns_w1, k chunks of 64
            const int k = blk - 136;
            float a = 0.f;
            #pragma unroll 4
            for (int d = 0; d < 64; ++d)
                a += ce[k * 64 + d] * ns_w1[(size_t)(k * 64 + d) * HD + t];
            ws[OFF_S1P + k * HD + t] = a;
        } else {
            // cc partial: ctx_enc @ wc (nm_w1 rows 0..1023), k chunks of 64
            const int k = blk - 152;
            float a0 = 0.f, a1 = 0.f;
            #pragma unroll 4
            for (int d = 0; d < 64; ++d) {
                float c = ce[k * 64 + d];
                const float* r2 = nm_w1 + (size_t)(k * 64 + d) * 512;
                a0 += c * r2[t]; a1 += c * r2[t + 256];
            }
            ws[OFF_CCP + k * 512 + t] = a0;
            ws[OFF_CCP + k * 512 + t + 256] = a1;
        }
    }
}

// ---------------- K5: per-b final: softmax weights, conformance, severity, outputs ----------------
__global__ __launch_bounds__(256) void k5(const float* __restrict__ ns_b1,
                                          const float* __restrict__ ns_w2,
                                          const float* __restrict__ ns_b2,
                                          const float* __restrict__ nm_b1,
                                          const float* __restrict__ nm_w2,
                                          const float* __restrict__ nm_b2,
                                          const float* __restrict__ sv_b1,
                                          const float* __restrict__ sv_w2,
                                          const float* __restrict__ sv_b2,
                                          const float* __restrict__ ws,
                                          float* __restrict__ out) {
    const int b = blockIdx.x;
    const int t = threadIdx.x;
    const int wave = t >> 6, lane = t & 63;
    __shared__ float g1[256];
    __shared__ float nw[64];
    __shared__ float base[512];
    __shared__ float w2s[512];
    __shared__ float conf[64];
    __shared__ float red[4];

    // g1 = gelu(ctx_enc @ ns_w1 + ns_b1)
    {
        float s = ns_b1[t];
        #pragma unroll
        for (int k = 0; k < 16; ++k) s += ws[OFF_S1P + k * HD + t];
        g1[t] = geluf(s);
    }
    __syncthreads();
    // norm weights: softmax over 64 logits (wave 0 only)
    if (t < 64) {
        float s = ns_b2[t];
        for (int h = 0; h < HD; ++h) s += g1[h] * ns_w2[(size_t)h * 64 + t];
        float m = s;
        #pragma unroll
        for (int o = 32; o >= 1; o >>= 1) m = fmaxf(m, __shfl_xor(m, o));
        float e = expf(s - m);
        float tot = e;
        #pragma unroll
        for (int o = 32; o >= 1; o >>= 1) tot += __shfl_xor(tot, o);
        nw[t] = e / tot;
    }
    // base[j] = cc[j] + aa[b][j] + nm_b1[j]; cache nm_w2 in LDS
    #pragma unroll
    for (int jj = 0; jj < 2; ++jj) {
        int j = t + jj * 256;
        float v = nm_b1[j];
        #pragma unroll
        for (int k = 0; k < 16; ++k) v += ws[OFF_CCP + k * 512 + j];
        #pragma unroll
        for (int k = 0; k < 8; ++k) v += ws[OFF_AAP + (size_t)(k * 64 + b) * 512 + j];
        base[j] = v;
        w2s[j] = nm_w2[j];
    }
    __syncthreads();
    // conformance[p] = sigmoid(sum_j gelu(base[j] + protopre[p][j]) * nm_w2[j] + nm_b2)
    const float b2 = nm_b2[0];
    for (int pi = 0; pi < 16; ++pi) {
        int p = wave * 16 + pi;
        const float* pp = ws + OFF_PROTOP + (size_t)p * 512;
        float s = 0.f;
        #pragma unroll
        for (int i = 0; i < 8; ++i) {
            int j = lane + 64 * i;
            s += geluf(base[j] + pp[j]) * w2s[j];
        }
        #pragma unroll
        for (int o = 32; o >= 1; o >>= 1) s += __shfl_xor(s, o);
        if (lane == 0) conf[p] = sigm(s + b2);
    }
    // severity: sv1[h] = gelu(sum partials + sv_b1); dot with sv_w2
    float sv = sv_b1[t];
    #pragma unroll
    for (int k = 0; k < 8; ++k) sv += ws[OFF_SVC + k * HD + t];
    #pragma unroll
    for (int k = 0; k < 8; ++k) sv += ws[OFF_SVA + (size_t)(k * 64 + b) * HD + t];
    float part = geluf(sv) * sv_w2[t];
    #pragma unroll
    for (int o = 32; o >= 1; o >>= 1) part += __shfl_xor(part, o);
    if (lane == 0) red[wave] = part;
    __syncthreads();
    if (t < 64) {
        float wcp = conf[t] * nw[t];
        #pragma unroll
        for (int o = 32; o >= 1; o >>= 1) wcp += __shfl_xor(wcp, o);
        if (t == 0) {
            float sev = sigm(red[0] + red[1] + red[2] + red[3] + sv_b2[0]);
            float wcf = wcp;
            float viol = 1.0f - wcf;
            out[b] = viol * sev * 0.1f;
            out[64 + b] = wcf;
            out[128 + b] = viol;
            out[192 + b] = sev;
        }
    }
}

extern "C" void kernel_launch(void* const* d_in, const int* in_sizes, int n_in,
                              void* d_out, int out_size, void* d_ws, size_t ws_size,
                              hipStream_t stream) {
    const float* x      = (const float*)d_in[0];
    const float* cb     = (const float*)d_in[1];
    const float* proto  = (const float*)d_in[2];
    const float* ce_w1  = (const float*)d_in[3];
    const float* ce_b1  = (const float*)d_in[4];
    const float* ce_w2  = (const float*)d_in[5];
    const float* ce_b2  = (const float*)d_in[6];
    const float* rms_w  = (const float*)d_in[7];
    const float* nm_w1  = (const float*)d_in[8];
    const float* nm_b1  = (const float*)d_in[9];
    const float* nm_w2  = (const float*)d_in[10];
    const float* nm_b2  = (const float*)d_in[11];
    const float* ns_w1  = (const float*)d_in[12];
    const float* ns_b1  = (const float*)d_in[13];
    const float* ns_w2  = (const float*)d_in[14];
    const float* ns_b2  = (const float*)d_in[15];
    const float* sv_w1  = (const float*)d_in[16];
    const float* sv_b1  = (const float*)d_in[17];
    const float* sv_w2  = (const float*)d_in[18];
    const float* sv_b2  = (const float*)d_in[19];
    float* ws  = (float*)d_ws;
    float* out = (float*)d_out;

    hipLaunchKernelGGL(k1, dim3(1056), dim3(256), 0, stream, x, cb, proto, ce_w1, nm_w1, ws);
    hipLaunchKernelGGL(k2, dim3(16), dim3(256), 0, stream, ce_b1, ce_w2, ws);
    hipLaunchKernelGGL(k4, dim3(168), dim3(256), 0, stream, nm_w1, ns_w1, sv_w1, ce_b2, rms_w, ws);
    hipLaunchKernelGGL(k5, dim3(64), dim3(256), 0, stream,
                       ns_b1, ns_w2, ns_b2, nm_b1, nm_w2, nm_b2, sv_b1, sv_w2, sv_b2, ws, out);
}

// Round 3
// 843.291 us; speedup vs baseline: 1.0532x; 1.0031x over previous
//
#include <hip/hip_runtime.h>
#include <math.h>

// Problem constants
#define BD   64      // batch
#define TD   2048    // seq
#define DD   1024    // D
#define HD   256     // H
#define KD   64      // K prototypes
#define CTXW 16

// ws layout (float offsets)
#define OFF_XPART  0u                         // 64*16*1024 = 1048576
#define OFF_H2     1052672u                   // 1024 (complete h2, bias included)
#define OFF_PROTOP 1135616u                   // 64*512
#define OFF_S1P    1168384u                   // 16*256
#define OFF_CCP    1172480u                   // 16*512
#define OFF_AAP    1180672u                   // 8*64*512
#define OFF_SVC    1442816u                   // 8*256
#define OFF_SVA    1444864u                   // 8*64*256  -> end 1575936 floats (~6.0 MB)

typedef float f4 __attribute__((ext_vector_type(4)));

__device__ __forceinline__ float geluf(float v) {
    return 0.5f * v * (1.0f + erff(v * 0.70710678118654752f));
}
__device__ __forceinline__ float sigm(float v) {
    return 1.0f / (1.0f + expf(-v));
}

// ---------------- K1: full ctx-encoder h2 slices + proto @ wp + x partial sums ----------------
// Small blocks FIRST so they dispatch early and hide under the x stream.
// Each h-block computes the FULL h1 (redundant x16, L2-absorbed) then its own
// 64-dim slice of the final h2 (bias included) -> no separate k2 stage needed.
__global__ __launch_bounds__(256) void k1(const float* __restrict__ x,
                                          const float* __restrict__ cb,
                                          const float* __restrict__ proto,
                                          const float* __restrict__ ce_w1,
                                          const float* __restrict__ ce_b1,
                                          const float* __restrict__ ce_w2,
                                          const float* __restrict__ ce_b2,
                                          const float* __restrict__ nm_w1,
                                          float* __restrict__ ws) {
    const int blk = blockIdx.x;
    const int t = threadIdx.x;
    if (blk < 16) {
        const int k = blk;
        __shared__ float ctxs[1024];
        __shared__ float g1s[256];
        __shared__ float hp[4][64];
        // ctx = mean over context window
        for (int i = t; i < 1024; i += 256) {
            float s = 0.f;
            #pragma unroll
            for (int w = 0; w < CTXW; ++w) s += cb[w * DD + i];
            ctxs[i] = s * (1.0f / 16.0f);
        }
        __syncthreads();
        // full h1: thread t owns h=t
        float s = ce_b1[t];
        #pragma unroll 4
        for (int d = 0; d < DD; ++d)
            s += ctxs[d] * ce_w1[(size_t)d * HD + t];
        g1s[t] = geluf(s);
        __syncthreads();
        // h2 slice dims [k*64, k*64+64): dl = t&63, partial over h-quarter hq = t>>6
        const int dl = t & 63, hq = t >> 6;
        const int d = k * 64 + dl;
        float a = 0.f;
        #pragma unroll 4
        for (int h = hq * 64; h < hq * 64 + 64; ++h)
            a += g1s[h] * ce_w2[(size_t)h * DD + d];
        hp[hq][dl] = a;
        __syncthreads();
        if (t < 64) {
            float v = hp[0][t] + hp[1][t] + hp[2][t] + hp[3][t] + ce_b2[k * 64 + t];
            ws[OFF_H2 + k * 64 + t] = v;
        }
    } else if (blk < 32) {
        // protopre[p][j] = proto[p] @ wp[:,j]  (wp = nm_w1 rows 2048..3071)
        const int idx = blk - 16;
        const int pg = idx >> 1, jh = idx & 1;
        __shared__ float pr[8][1024];
        for (int i = t; i < 8 * 1024; i += 256) pr[i >> 10][i & 1023] = proto[(size_t)(pg * 8) * DD + i];
        __syncthreads();
        const int j = jh * 256 + t;
        float acc[8];
        #pragma unroll
        for (int p = 0; p < 8; ++p) acc[p] = 0.f;
        #pragma unroll 4
        for (int d = 0; d < DD; ++d) {
            float w = nm_w1[(size_t)(2048 + d) * 512 + j];
            #pragma unroll
            for (int p = 0; p < 8; ++p) acc[p] += pr[p][d] * w;
        }
        #pragma unroll
        for (int p = 0; p < 8; ++p) ws[OFF_PROTOP + (size_t)(pg * 8 + p) * 512 + j] = acc[p];
    } else {
        // x partial sums: block = (b, tchunk of 128 rows)
        const int xb = blk - 32;
        const int b = xb >> 4, tc = xb & 15;
        const f4* p = (const f4*)(x + (size_t)(b * TD + tc * 128) * DD) + t;
        f4 acc = {0.f, 0.f, 0.f, 0.f};
        #pragma unroll 8
        for (int i = 0; i < 128; ++i) {
            f4 v = __builtin_nontemporal_load(p + (size_t)i * 256);
            acc += v;
        }
        ((f4*)(ws + OFF_XPART + (size_t)xb * DD))[t] = acc;
    }
}

// ---------------- K4: aa partials, sv partials, s1 partials, cc partials ----------------
// ctx_enc recomputed per-block from the complete h2 (4 KB read + block RMS);
// action slices recomputed from x partials.
__global__ __launch_bounds__(256) void k4(const float* __restrict__ nm_w1,
                                          const float* __restrict__ ns_w1,
                                          const float* __restrict__ sv_w1,
                                          const float* __restrict__ rms_w,
                                          float* __restrict__ ws) {
    const int blk = blockIdx.x;
    const int t = threadIdx.x;
    __shared__ float al[8][128];
    __shared__ float ce[1024];
    __shared__ float red[4];
    __shared__ float totsh;

    if (blk < 128) {
        // action-slice build: bg over b-groups of 8, dc over d-chunks of 128
        const int ii = (blk < 64) ? blk : (blk - 64);
        const int dc = ii >> 3, bg = ii & 7;
        for (int i = t; i < 1024; i += 256) {
            int p = i >> 7, d = i & 127;
            int row = (bg * 8 + p) * 16;
            float s = 0.f;
            #pragma unroll
            for (int k = 0; k < 16; ++k)
                s += ws[OFF_XPART + (size_t)(row + k) * DD + dc * 128 + d];
            al[p][d] = s * (1.0f / 2048.0f);
        }
        __syncthreads();
        if (blk < 64) {
            // aa partial: action @ wa (wa = nm_w1 rows 1024..2047)
            float acc0[8], acc1[8];
            #pragma unroll
            for (int p = 0; p < 8; ++p) { acc0[p] = 0.f; acc1[p] = 0.f; }
            for (int d = 0; d < 128; ++d) {
                const float* wrow = nm_w1 + (size_t)(1024 + dc * 128 + d) * 512;
                float w0 = wrow[t], w1 = wrow[t + 256];
                #pragma unroll
                for (int p = 0; p < 8; ++p) {
                    float a = al[p][d];
                    acc0[p] += a * w0; acc1[p] += a * w1;
                }
            }
            #pragma unroll
            for (int p = 0; p < 8; ++p) {
                size_t base = OFF_AAP + (size_t)(dc * 64 + bg * 8 + p) * 512;
                ws[base + t] = acc0[p];
                ws[base + t + 256] = acc1[p];
            }
        } else {
            // sv action-half partial
            float acc[8];
            #pragma unroll
            for (int p = 0; p < 8; ++p) acc[p] = 0.f;
            for (int d = 0; d < 128; ++d) {
                float w = sv_w1[(size_t)(1024 + dc * 128 + d) * HD + t];
                #pragma unroll
                for (int p = 0; p < 8; ++p) acc[p] += al[p][d] * w;
            }
            #pragma unroll
            for (int p = 0; p < 8; ++p)
                ws[OFF_SVA + (size_t)(dc * 64 + bg * 8 + p) * HD + t] = acc[p];
        }
    } else {
        // ctx_enc from the complete h2 (bias already included): RMS-norm in-block
        float4 acc = ((const float4*)(ws + OFF_H2))[t];
        float ss = acc.x * acc.x + acc.y * acc.y + acc.z * acc.z + acc.w * acc.w;
        const int wave = t >> 6, lane = t & 63;
        #pragma unroll
        for (int o = 32; o >= 1; o >>= 1) ss += __shfl_xor(ss, o);
        if (lane == 0) red[wave] = ss;
        __syncthreads();
        if (t == 0) totsh = red[0] + red[1] + red[2] + red[3];
        __syncthreads();
        float r = rsqrtf(totsh * (1.0f / 1024.0f) + 1e-6f);
        float4 w = ((const float4*)rms_w)[t];
        ce[4 * t + 0] = acc.x * r * w.x;
        ce[4 * t + 1] = acc.y * r * w.y;
        ce[4 * t + 2] = acc.z * r * w.z;
        ce[4 * t + 3] = acc.w * r * w.w;
        __syncthreads();

        if (blk < 136) {
            // sv ctx-half partial: dc in [0,8)
            const int dc = blk - 128;
            float a = 0.f;
            #pragma unroll 4
            for (int d = 0; d < 128; ++d)
                a += ce[dc * 128 + d] * sv_w1[(size_t)(dc * 128 + d) * HD + t];
            ws[OFF_SVC + dc * HD + t] = a;
        } else if (blk < 152) {
            // s1 partial: ctx_enc @ ns_w1, k chunks of 64
            const int k = blk - 136;
            float a = 0.f;
            #pragma unroll 4
            for (int d = 0; d < 64; ++d)
                a += ce[k * 64 + d] * ns_w1[(size_t)(k * 64 + d) * HD + t];
            ws[OFF_S1P + k * HD + t] = a;
        } else {
            // cc partial: ctx_enc @ wc (nm_w1 rows 0..1023), k chunks of 64
            const int k = blk - 152;
            float a0 = 0.f, a1 = 0.f;
            #pragma unroll 4
            for (int d = 0; d < 64; ++d) {
                float c = ce[k * 64 + d];
                const float* r2 = nm_w1 + (size_t)(k * 64 + d) * 512;
                a0 += c * r2[t]; a1 += c * r2[t + 256];
            }
            ws[OFF_CCP + k * 512 + t] = a0;
            ws[OFF_CCP + k * 512 + t + 256] = a1;
        }
    }
}

// ---------------- K5: per-b final: softmax weights, conformance, severity, outputs ----------------
__global__ __launch_bounds__(256) void k5(const float* __restrict__ ns_b1,
                                          const float* __restrict__ ns_w2,
                                          const float* __restrict__ ns_b2,
                                          const float* __restrict__ nm_b1,
                                          const float* __restrict__ nm_w2,
                                          const float* __restrict__ nm_b2,
                                          const float* __restrict__ sv_b1,
                                          const float* __restrict__ sv_w2,
                                          const float* __restrict__ sv_b2,
                                          const float* __restrict__ ws,
                                          float* __restrict__ out) {
    const int b = blockIdx.x;
    const int t = threadIdx.x;
    const int wave = t >> 6, lane = t & 63;
    __shared__ float g1[256];
    __shared__ float nw[64];
    __shared__ float base[512];
    __shared__ float w2s[512];
    __shared__ float conf[64];
    __shared__ float red[4];

    // g1 = gelu(ctx_enc @ ns_w1 + ns_b1)
    {
        float s = ns_b1[t];
        #pragma unroll
        for (int k = 0; k < 16; ++k) s += ws[OFF_S1P + k * HD + t];
        g1[t] = geluf(s);
    }
    __syncthreads();
    // norm weights: softmax over 64 logits (wave 0 only)
    if (t < 64) {
        float s = ns_b2[t];
        for (int h = 0; h < HD; ++h) s += g1[h] * ns_w2[(size_t)h * 64 + t];
        float m = s;
        #pragma unroll
        for (int o = 32; o >= 1; o >>= 1) m = fmaxf(m, __shfl_xor(m, o));
        float e = expf(s - m);
        float tot = e;
        #pragma unroll
        for (int o = 32; o >= 1; o >>= 1) tot += __shfl_xor(tot, o);
        nw[t] = e / tot;
    }
    // base[j] = cc[j] + aa[b][j] + nm_b1[j]; cache nm_w2 in LDS
    #pragma unroll
    for (int jj = 0; jj < 2; ++jj) {
        int j = t + jj * 256;
        float v = nm_b1[j];
        #pragma unroll
        for (int k = 0; k < 16; ++k) v += ws[OFF_CCP + k * 512 + j];
        #pragma unroll
        for (int k = 0; k < 8; ++k) v += ws[OFF_AAP + (size_t)(k * 64 + b) * 512 + j];
        base[j] = v;
        w2s[j] = nm_w2[j];
    }
    __syncthreads();
    // conformance[p] = sigmoid(sum_j gelu(base[j] + protopre[p][j]) * nm_w2[j] + nm_b2)
    const float b2 = nm_b2[0];
    for (int pi = 0; pi < 16; ++pi) {
        int p = wave * 16 + pi;
        const float* pp = ws + OFF_PROTOP + (size_t)p * 512;
        float s = 0.f;
        #pragma unroll
        for (int i = 0; i < 8; ++i) {
            int j = lane + 64 * i;
            s += geluf(base[j] + pp[j]) * w2s[j];
        }
        #pragma unroll
        for (int o = 32; o >= 1; o >>= 1) s += __shfl_xor(s, o);
        if (lane == 0) conf[p] = sigm(s + b2);
    }
    // severity: sv1[h] = gelu(sum partials + sv_b1); dot with sv_w2
    float sv = sv_b1[t];
    #pragma unroll
    for (int k = 0; k < 8; ++k) sv += ws[OFF_SVC + k * HD + t];
    #pragma unroll
    for (int k = 0; k < 8; ++k) sv += ws[OFF_SVA + (size_t)(k * 64 + b) * HD + t];
    float part = geluf(sv) * sv_w2[t];
    #pragma unroll
    for (int o = 32; o >= 1; o >>= 1) part += __shfl_xor(part, o);
    if (lane == 0) red[wave] = part;
    __syncthreads();
    if (t < 64) {
        float wcp = conf[t] * nw[t];
        #pragma unroll
        for (int o = 32; o >= 1; o >>= 1) wcp += __shfl_xor(wcp, o);
        if (t == 0) {
            float sev = sigm(red[0] + red[1] + red[2] + red[3] + sv_b2[0]);
            float wcf = wcp;
            float viol = 1.0f - wcf;
            out[b] = viol * sev * 0.1f;
            out[64 + b] = wcf;
            out[128 + b] = viol;
            out[192 + b] = sev;
        }
    }
}

extern "C" void kernel_launch(void* const* d_in, const int* in_sizes, int n_in,
                              void* d_out, int out_size, void* d_ws, size_t ws_size,
                              hipStream_t stream) {
    const float* x      = (const float*)d_in[0];
    const float* cb     = (const float*)d_in[1];
    const float* proto  = (const float*)d_in[2];
    const float* ce_w1  = (const float*)d_in[3];
    const float* ce_b1  = (const float*)d_in[4];
    const float* ce_w2  = (const float*)d_in[5];
    const float* ce_b2  = (const float*)d_in[6];
    const float* rms_w  = (const float*)d_in[7];
    const float* nm_w1  = (const float*)d_in[8];
    const float* nm_b1  = (const float*)d_in[9];
    const float* nm_w2  = (const float*)d_in[10];
    const float* nm_b2  = (const float*)d_in[11];
    const float* ns_w1  = (const float*)d_in[12];
    const float* ns_b1  = (const float*)d_in[13];
    const float* ns_w2  = (const float*)d_in[14];
    const float* ns_b2  = (const float*)d_in[15];
    const float* sv_w1  = (const float*)d_in[16];
    const float* sv_b1  = (const float*)d_in[17];
    const float* sv_w2  = (const float*)d_in[18];
    const float* sv_b2  = (const float*)d_in[19];
    float* ws  = (float*)d_ws;
    float* out = (float*)d_out;

    hipLaunchKernelGGL(k1, dim3(1056), dim3(256), 0, stream,
                       x, cb, proto, ce_w1, ce_b1, ce_w2, ce_b2, nm_w1, ws);
    hipLaunchKernelGGL(k4, dim3(168), dim3(256), 0, stream, nm_w1, ns_w1, sv_w1, rms_w, ws);
    hipLaunchKernelGGL(k5, dim3(64), dim3(256), 0, stream,
                       ns_b1, ns_w2, ns_b2, nm_b1, nm_w2, nm_b2, sv_b1, sv_w2, sv_b2, ws, out);
}